// Round 2
// baseline (160.952 us; speedup 1.0000x reference)
//
#include <hip/hip_runtime.h>
#include <hip/hip_bf16.h>

#define CIN  64
#define HH   128
#define WW   128
#define COUT 128
#define HO   126
#define WO   126
#define NB   32
#define HW   (HH * WW)

typedef __bf16 bf16x8 __attribute__((ext_vector_type(8)));
typedef float f32x4 __attribute__((ext_vector_type(4)));

// reorder weight [128][64][3][3] f32 -> ws [9][128][64] bf16
__global__ void wreorder_3556(const float* __restrict__ w, unsigned short* __restrict__ ws) {
    int idx = blockIdx.x * 256 + threadIdx.x;
    if (idx >= 9 * 128 * 64) return;
    int s = idx >> 13;
    int r = idx & 8191;
    int cout = r >> 6, ci = r & 63;
    __bf16 h = (__bf16)w[cout * 576 + ci * 9 + s];
    ws[idx] = __builtin_bit_cast(unsigned short, h);
}

// LDS: xs[row(3)][col(130)][ci(64)] bf16, ci-granule XOR-swizzled by col&7; + pmin
#define XS_BYTES   (3 * 130 * 128)
#define SMEM_BYTES (XS_BYTES + 2 * 128 * 4)

template<bool USE_WS>
__global__ __launch_bounds__(256, 3)
void conv_min_tanh_3556(const float* __restrict__ x, const float* __restrict__ w,
                        const float* __restrict__ bias,
                        const unsigned short* __restrict__ wsr,
                        float* __restrict__ out) {
    __shared__ __align__(16) unsigned char smem[SMEM_BYTES];
    unsigned char* xs = smem;
    float* pmin = (float*)(smem + XS_BYTES);

    // XCD-chunked swizzle: adjacent ho -> same XCD L2 (4032 % 8 == 0)
    const int bid = blockIdx.x;
    const int blk = (bid & 7) * (NB * HO / 8) + (bid >> 3);
    const int b  = blk / HO;
    const int ho = blk - b * HO;

    const int tid = threadIdx.x;

    // ---- stage x tile with float4 loads: 768 quad-granules, 3 iters x 256 threads
    {
        const float* xb = x + (size_t)b * (CIN * HW);
        #pragma unroll
        for (int it = 0; it < 3; ++it) {
            int item = it * 256 + tid;          // 0..767
            int col4 = item & 31;               // group of 4 cols
            int cig  = (item >> 5) & 7;         // group of 8 ci
            int row  = item >> 8;               // 0..2
            const float* src = xb + (size_t)(cig * 8) * HW + (size_t)(ho + row) * WW + col4 * 4;
            f32x4 v[8];
            #pragma unroll
            for (int j = 0; j < 8; ++j) v[j] = *(const f32x4*)(src + (size_t)j * HW);
            #pragma unroll
            for (int c = 0; c < 4; ++c) {
                bf16x8 g;
                #pragma unroll
                for (int j = 0; j < 8; ++j) g[j] = (__bf16)v[j][c];
                int col = col4 * 4 + c;
                int addr = (row * 130 + col) * 128 + ((cig ^ (col & 7)) << 4);
                *(bf16x8*)(xs + addr) = g;
            }
        }
    }

    const int lane  = tid & 63;
    const int wid   = tid >> 6;
    const int waveM = wid >> 1, waveN = wid & 1;
    const int lr = lane & 15, lg = lane >> 4;

    __syncthreads();   // xs ready; no more barriers until epilogue

    f32x4 acc[4][4] = {};
    const unsigned short* wb = USE_WS ? (wsr + (size_t)(waveM * 64 + lr) * 64 + lg * 8) : nullptr;

    #pragma unroll
    for (int s = 0; s < 9; ++s) {
        const int kh = s / 3, kw = s - kh * 3;   // compile-time (full unroll)
        bf16x8 af[4][2], bfr[4][2];
        #pragma unroll
        for (int m = 0; m < 4; ++m)
            #pragma unroll
            for (int kk = 0; kk < 2; ++kk) {
                if (USE_WS) {
                    af[m][kk] = *(const bf16x8*)(wb + s * 8192 + m * 1024 + kk * 32);
                } else {
                    #pragma unroll
                    for (int j = 0; j < 8; ++j)
                        af[m][kk][j] = (__bf16)w[(waveM * 64 + m * 16 + lr) * 576 +
                                                 (kk * 32 + lg * 8 + j) * 9 + s];
                }
            }
        #pragma unroll
        for (int n = 0; n < 4; ++n)
            #pragma unroll
            for (int kk = 0; kk < 2; ++kk) {
                int col = waveN * 64 + n * 16 + lr + kw;      // <= 129
                int g = kk * 4 + lg;                           // 16B ci-granule
                int addr = (kh * 130 + col) * 128 + ((g ^ (col & 7)) << 4);
                bfr[n][kk] = *(const bf16x8*)(xs + addr);
            }
        #pragma unroll
        for (int kk = 0; kk < 2; ++kk)
            #pragma unroll
            for (int m = 0; m < 4; ++m)
                #pragma unroll
                for (int n = 0; n < 4; ++n)
                    acc[m][n] = __builtin_amdgcn_mfma_f32_16x16x32_bf16(
                        af[m][kk], bfr[n][kk], acc[m][n], 0, 0, 0);
    }

    // ---- epilogue: +bias, min over cout, tanh(tanh), store
    float pm[4] = {1e30f, 1e30f, 1e30f, 1e30f};
    #pragma unroll
    for (int m = 0; m < 4; ++m) {
        #pragma unroll
        for (int r = 0; r < 4; ++r) {
            int cout = waveM * 64 + m * 16 + lg * 4 + r;   // D row mapping
            float bv = bias[cout];
            #pragma unroll
            for (int n = 0; n < 4; ++n)
                pm[n] = fminf(pm[n], acc[m][n][r] + bv);
        }
    }
    #pragma unroll
    for (int n = 0; n < 4; ++n) {
        pm[n] = fminf(pm[n], __shfl_xor(pm[n], 16, 64));
        pm[n] = fminf(pm[n], __shfl_xor(pm[n], 32, 64));
    }
    if (lg == 0) {
        #pragma unroll
        for (int n = 0; n < 4; ++n) {
            int px = waveN * 64 + n * 16 + lr;            // D col mapping
            pmin[waveM * 128 + px] = pm[n];
        }
    }
    __syncthreads();
    if (tid < WO) {
        float v = fminf(pmin[tid], pmin[128 + tid]);
        v = tanhf(tanhf(v));
        out[((size_t)b * HO + ho) * WO + tid] = v;
    }
}

extern "C" void kernel_launch(void* const* d_in, const int* in_sizes, int n_in,
                              void* d_out, int out_size, void* d_ws, size_t ws_size,
                              hipStream_t stream) {
    const float* x    = (const float*)d_in[0];
    const float* w    = (const float*)d_in[1];
    const float* bias = (const float*)d_in[2];
    float* out = (float*)d_out;

    const size_t ws_needed = (size_t)9 * 128 * 64 * 2;   // 147456 B
    if (ws_size >= ws_needed) {
        unsigned short* wsb = (unsigned short*)d_ws;
        wreorder_3556<<<288, 256, 0, stream>>>(w, wsb);
        conv_min_tanh_3556<true><<<NB * HO, 256, 0, stream>>>(x, w, bias, wsb, out);
    } else {
        conv_min_tanh_3556<false><<<NB * HO, 256, 0, stream>>>(x, w, bias, nullptr, out);
    }
}